// Round 1
// baseline (177.099 us; speedup 1.0000x reference)
//
#include <hip/hip_runtime.h>

// Shape fixed by reference: (2,1,160,160,160) fp32, window 11, zero-pad box filter.
// Fields reduced via u=x+y, v=x-y: box{u, v, u^2, v^2} packed in one float4.
#define DIMX 160
#define DIMY 160
#define DIMZ 160
#define BC   2
#define NTOT (BC * DIMZ * DIMY * DIMX)   // 8,192,000
#define PAD  5
#define TS   16                  // tile size in H and W
#define HS   26                  // TS + 2*PAD rows
#define XS4  10                  // stage row stride in float4 (8 used + 2 pad for banking)
#define WPS  17                  // wp row stride in float4 (breaks bank aliasing)
#define CD   20                  // D-chunk per block
#define NCH  (DIMZ / CD)         // 8
#define NTH  (DIMY / TS)         // 10
#define NTW  (DIMX / TS)         // 10
#define NBLK (NCH * BC * NTH * NTW)  // 1600 blocks

static_assert(NTOT == 8192000, "size mismatch");

__device__ __forceinline__ float4 f4add(float4 a, float4 b) {
  return make_float4(a.x + b.x, a.y + b.y, a.z + b.z, a.w + b.w);
}
__device__ __forceinline__ float4 f4sub(float4 a, float4 b) {
  return make_float4(a.x - b.x, a.y - b.y, a.z - b.z, a.w - b.w);
}

// Ring slot update with compile-time index K (keeps ring[] in VGPRs).
#define RING_CASE(K) case K: {                 \
    sums = f4add(sums, f4sub(Sv, ring[K]));    \
    ring[K] = Sv;                              \
  } break;

__global__ __launch_bounds__(256) void fused_ssim(const float* __restrict__ X,
                                                  const float* __restrict__ Y,
                                                  float* __restrict__ pssim,
                                                  float* __restrict__ pl1) {
  __shared__ float4 us4[HS * XS4];   // staged u slab (26 rows x 8 used float4)
  __shared__ float4 vs4[HS * XS4];   // staged v slab
  __shared__ float4 wpf[HS * WPS];   // W-passed {su,sv,suu,svv}, stride 17

  const int tid = threadIdx.x;
  const int bx  = blockIdx.x;
  const int tw  = bx % NTW;
  const int th  = (bx / NTW) % NTH;
  const int b   = (bx / (NTW * NTH)) % BC;
  const int ch  =  bx / (NTW * NTH * BC);
  const int h0 = th * TS, w0 = tw * TS, c0 = ch * CD;
  const size_t bbase = (size_t)b * (DIMZ * DIMY * DIMX);

  // staging decomposition: 208 threads = 26 rows x 8 float4-cols (w0-8 .. w0+23)
  const int sr  = tid >> 3, sc4 = tid & 7;
  const int sgh = h0 - PAD + sr;
  const int sgw = w0 - 8 + (sc4 << 2);
  const bool sok = (tid < 208) && ((unsigned)sgh < (unsigned)DIMY) &&
                   ((unsigned)sgw < (unsigned)DIMX);
  const bool l1own = (sr >= PAD) && (sr < PAD + TS) && (sc4 >= 2) && (sc4 < 6);
  const size_t sgoff = bbase + (size_t)sgh * DIMX + sgw;   // only used when sok

  // H-pass / ring ownership: one (h,w) output column per thread
  const int hh = tid >> 4, ww = tid & 15;
  const int hbase = hh * WPS + ww;   // wpf row h..h+10 sum

  float4 ring[11];
#pragma unroll
  for (int k = 0; k < 11; ++k) ring[k] = make_float4(0.f, 0.f, 0.f, 0.f);
  float4 sums = make_float4(0.f, 0.f, 0.f, 0.f);
  float l1loc = 0.f, ssloc = 0.f;

  const float inv = 1.0f / 1331.0f;             // 1/11^3
  const float c1  = 0.01f / (4096.f * 4096.f);  // K1 / data_range^2 (faithful to ref)
  const float c2  = 0.03f / (4096.f * 4096.f);

  // prefetch first slab (d = c0-PAD) into regs
  float4 xq = make_float4(0.f, 0.f, 0.f, 0.f), yq = xq;
  if (sok && (unsigned)(c0 - PAD) < (unsigned)DIMZ) {
    const size_t g = sgoff + (size_t)(c0 - PAD) * (DIMY * DIMX);
    xq = *(const float4*)(X + g);
    yq = *(const float4*)(Y + g);
  }

  int ph = (c0 - PAD + 22) % 11;   // uniform ring phase

  for (int d = c0 - PAD; d < c0 + CD + PAD; ++d) {
    const bool dval = (unsigned)d < (unsigned)DIMZ;
    const bool dIn  = (d >= c0) && (d < c0 + CD);

    // --- stage u,v from prefetched regs; fuse smooth-L1; issue next prefetch ---
    if (tid < 208) {
      if (dval) {
        const float4 u = f4add(xq, yq);
        const float4 v = f4sub(xq, yq);
        us4[sr * XS4 + sc4] = u;
        vs4[sr * XS4 + sc4] = v;
        if (dIn && l1own) {
          const float a0 = fabsf(v.x), a1 = fabsf(v.y);
          const float a2 = fabsf(v.z), a3 = fabsf(v.w);
          l1loc += (a0 < 1.f) ? 0.5f * a0 * a0 : a0 - 0.5f;
          l1loc += (a1 < 1.f) ? 0.5f * a1 * a1 : a1 - 0.5f;
          l1loc += (a2 < 1.f) ? 0.5f * a2 * a2 : a2 - 0.5f;
          l1loc += (a3 < 1.f) ? 0.5f * a3 * a3 : a3 - 0.5f;
        }
      }
      const int dn = d + 1;
      if (sok && (unsigned)dn < (unsigned)DIMZ) {
        const size_t g = sgoff + (size_t)dn * (DIMY * DIMX);
        xq = *(const float4*)(X + g);   // in flight across the whole slab body
        yq = *(const float4*)(Y + g);
      } else {
        xq = make_float4(0.f, 0.f, 0.f, 0.f);
        yq = make_float4(0.f, 0.f, 0.f, 0.f);
      }
    }
    __syncthreads();

    // --- W-pass: 208 threads x 2 sliding outputs; float2 reads keep the
    //     11-window start at a COMPILE-TIME offset (t[1]) for every lane ---
    if (dval && tid < 208) {
      const int wr = tid >> 3, wg = tid & 7;
      const int rb2 = wr * (XS4 * 2) + wg + 1;   // float2 index, covers idx 2wg+2..2wg+17
      const int ow  = wr * WPS + (wg << 1);
      const float2* u2 = (const float2*)us4;
      const float2* v2 = (const float2*)vs4;
      float su0, su1, suu0, suu1, sv0, sv1, svv0, svv1;
      {  // field u: outputs w=2wg (idx t[1..11]) and w=2wg+1 (idx t[2..12])
        float t[16];
#pragma unroll
        for (int k = 0; k < 8; ++k) {
          const float2 q = u2[rb2 + k];
          t[2 * k] = q.x; t[2 * k + 1] = q.y;
        }
        float s = 0.f, ss = 0.f;
#pragma unroll
        for (int j = 1; j <= 11; ++j) { s += t[j]; ss = fmaf(t[j], t[j], ss); }
        su0 = s; suu0 = ss;
        su1 = s + t[12] - t[1];
        suu1 = fmaf(t[12], t[12], fmaf(-t[1], t[1], ss));
      }
      {  // field v
        float t[16];
#pragma unroll
        for (int k = 0; k < 8; ++k) {
          const float2 q = v2[rb2 + k];
          t[2 * k] = q.x; t[2 * k + 1] = q.y;
        }
        float s = 0.f, ss = 0.f;
#pragma unroll
        for (int j = 1; j <= 11; ++j) { s += t[j]; ss = fmaf(t[j], t[j], ss); }
        sv0 = s; svv0 = ss;
        sv1 = s + t[12] - t[1];
        svv1 = fmaf(t[12], t[12], fmaf(-t[1], t[1], ss));
      }
      wpf[ow]     = make_float4(su0, sv0, suu0, svv0);
      wpf[ow + 1] = make_float4(su1, sv1, suu1, svv1);
    }
    __syncthreads();

    // --- H-pass: ALL 256 threads, 1 output each -> Sv directly in register.
    //     (Sb redistribution buffer + 3rd barrier eliminated.) ---
    float4 Sv = make_float4(0.f, 0.f, 0.f, 0.f);
    if (dval) {
      float4 S = wpf[hbase];
#pragma unroll
      for (int t = 1; t <= 10; ++t) S = f4add(S, wpf[hbase + t * WPS]);
      Sv = S;
    }

    // --- D-window ring update (registers, uniform switch) ---
    switch (ph) {
      RING_CASE(0) RING_CASE(1) RING_CASE(2) RING_CASE(3) RING_CASE(4)
      RING_CASE(5) RING_CASE(6) RING_CASE(7) RING_CASE(8) RING_CASE(9)
      RING_CASE(10)
    }
    ph = (ph == 10) ? 0 : ph + 1;

    // --- SSIM for output voxel dc = d-5 (u/v algebra) ---
    if (d >= c0 + PAD) {
      const float mu_u = sums.x * inv, mu_v = sums.y * inv;
      const float Euu  = sums.z * inv, Evv  = sums.w * inv;
      const float P = mu_u * mu_u, Q = mu_v * mu_v;
      const float sgu = Euu - P, sgv = Evv - Q;
      const float num = (0.5f * (P - Q) + c1) * (0.5f * (sgu - sgv) + c2);
      const float den = (0.5f * (P + Q) + c1) * (0.5f * (sgu + sgv) + c2);
      const float ssim = num * __builtin_amdgcn_rcpf(den + 1e-8f);
      const float val  = 0.5f * (1.f - ssim);
      ssloc += fminf(fmaxf(val, 0.f), 1.f);
    }
  }

  // --- block reduction -> per-block partials ---
#pragma unroll
  for (int off = 32; off > 0; off >>= 1) {
    ssloc += __shfl_down(ssloc, off, 64);
    l1loc += __shfl_down(l1loc, off, 64);
  }
  __syncthreads();                 // LDS compute use done; reuse us4 as scratch
  float* scr = (float*)us4;
  const int lane = tid & 63, wv = tid >> 6;
  if (lane == 0) {
    scr[wv * 2]     = ssloc;
    scr[wv * 2 + 1] = l1loc;
  }
  __syncthreads();
  if (tid == 0) {
    pssim[bx] = scr[0] + scr[2] + scr[4] + scr[6];
    pl1[bx]   = scr[1] + scr[3] + scr[5] + scr[7];
  }
}

// Final: reduce 1600 + 1600 partials in double, emit scalar loss.
__global__ __launch_bounds__(256) void final_reduce(const float* __restrict__ pssim,
                                                    const float* __restrict__ pl1,
                                                    float* __restrict__ out) {
  double s = 0.0, l = 0.0;
  for (int i = threadIdx.x; i < NBLK; i += 256) {
    s += (double)pssim[i];
    l += (double)pl1[i];
  }
#pragma unroll
  for (int off = 32; off > 0; off >>= 1) {
    s += __shfl_down(s, off, 64);
    l += __shfl_down(l, off, 64);
  }
  __shared__ double sm[8];
  const int lane = threadIdx.x & 63, wv = threadIdx.x >> 6;
  if (lane == 0) { sm[wv * 2] = s; sm[wv * 2 + 1] = l; }
  __syncthreads();
  if (threadIdx.x == 0) {
    const double ssm = (sm[0] + sm[2] + sm[4] + sm[6]) / (double)NTOT;
    const double l1m = (sm[1] + sm[3] + sm[5] + sm[7]) / (double)NTOT;
    out[0] = (float)(0.85 * ssm + 0.15 * l1m);
  }
}

extern "C" void kernel_launch(void* const* d_in, const int* in_sizes, int n_in,
                              void* d_out, int out_size, void* d_ws, size_t ws_size,
                              hipStream_t stream) {
  const float* X = (const float*)d_in[0];
  const float* Y = (const float*)d_in[1];
  float* out = (float*)d_out;

  float* pssim = (float*)d_ws;        // NBLK floats
  float* pl1   = pssim + NBLK;        // NBLK floats

  fused_ssim<<<NBLK, 256, 0, stream>>>(X, Y, pssim, pl1);
  final_reduce<<<1, 256, 0, stream>>>(pssim, pl1, out);
}